// Round 1
// baseline (367.167 us; speedup 1.0000x reference)
//
#include <hip/hip_runtime.h>

#define CROP_H 14
#define CROP_W 14
#define IMG_H 200
#define IMG_W 200
#define IMG_C 256

// 1 thread = 1 output element, linear over ((b*C + c)*14 + y)*14 + x.
// Writes fully coalesced; reads are 4 bilinear taps in the (n,c) plane.
__global__ __launch_bounds__(256) void crop_resize_kernel(
    const float* __restrict__ image,   // (8,256,200,200)
    const float* __restrict__ boxes,   // (1000,4)
    const int*   __restrict__ box_idx, // (1000,)
    float*       __restrict__ out,     // (1000,256,14,14)
    int total)
{
    int idx = blockIdx.x * blockDim.x + threadIdx.x;
    if (idx >= total) return;

    int x = idx % CROP_W;
    int t = idx / CROP_W;
    int y = t % CROP_H;
    t /= CROP_H;
    int c = t % IMG_C;
    int b = t / IMG_C;

    float y1 = boxes[b * 4 + 0];
    float x1 = boxes[b * 4 + 1];
    float y2 = boxes[b * 4 + 2];
    float x2 = boxes[b * 4 + 3];

    // Match reference arithmetic order exactly (IEEE divide, no fast-math).
    float h_scale = (y2 - y1) * (float)(IMG_H - 1) / (float)(CROP_H - 1);
    float w_scale = (x2 - x1) * (float)(IMG_W - 1) / (float)(CROP_W - 1);

    float in_y = y1 * (float)(IMG_H - 1) + (float)y * h_scale;
    float in_x = x1 * (float)(IMG_W - 1) + (float)x * w_scale;

    bool bad = (in_y > (float)(IMG_H - 1)) || (in_y < 0.0f) ||
               (in_x > (float)(IMG_W - 1)) || (in_x < 0.0f);
    if (bad) { out[idx] = 0.0f; return; }

    int ty = (int)floorf(in_y);
    int by = (int)ceilf(in_y);
    int lx = (int)floorf(in_x);
    int rx = (int)ceilf(in_x);
    float yl = in_y - (float)ty;
    float xl = in_x - (float)lx;

    int n = box_idx[b];
    const float* __restrict__ plane =
        image + ((size_t)n * IMG_C + c) * (size_t)(IMG_H * IMG_W);

    float tl = plane[ty * IMG_W + lx];
    float tr = plane[ty * IMG_W + rx];
    float bl = plane[by * IMG_W + lx];
    float br = plane[by * IMG_W + rx];

    float top = tl + xl * (tr - tl);
    float bot = bl + xl * (br - bl);
    out[idx] = top + yl * (bot - top);
}

extern "C" void kernel_launch(void* const* d_in, const int* in_sizes, int n_in,
                              void* d_out, int out_size, void* d_ws, size_t ws_size,
                              hipStream_t stream) {
    const float* image   = (const float*)d_in[0];
    const float* boxes   = (const float*)d_in[1];
    const int*   box_idx = (const int*)d_in[2];
    float* out = (float*)d_out;

    int total = out_size; // 1000*256*14*14 = 50,176,000
    int block = 256;
    int grid = (total + block - 1) / block;
    crop_resize_kernel<<<grid, block, 0, stream>>>(image, boxes, box_idx, out, total);
}

// Round 2
// 284.034 us; speedup vs baseline: 1.2927x; 1.2927x over previous
//
#include <hip/hip_runtime.h>

#define CROP_H 14
#define CROP_W 14
#define IMG_H 200
#define IMG_W 200
#define IMG_C 256
#define N_IMG 8
#define N_BOXES 1000
#define ELEMS_PER_BOX (IMG_C * CROP_H * CROP_W)   // 50176
#define BLOCKS_PER_BOX (ELEMS_PER_BOX / 256)      // 196

// Kernel A: stable-bin the 1000 boxes by image index n (8 bins).
// 1 block, 512 threads = 8 waves; wave w owns bin w. Deterministic.
__global__ __launch_bounds__(512) void bin_boxes_kernel(
    const int* __restrict__ box_idx, int* __restrict__ order)
{
    __shared__ int counts[N_IMG];
    __shared__ int offsets[N_IMG];
    int tid  = threadIdx.x;
    int wave = tid >> 6;
    int lane = tid & 63;

    // Count boxes in my bin.
    int cnt = 0;
    for (int i = lane; i < N_BOXES; i += 64) cnt += (box_idx[i] == wave) ? 1 : 0;
    for (int off = 32; off; off >>= 1) cnt += __shfl_down(cnt, off);
    if (lane == 0) counts[wave] = cnt;
    __syncthreads();
    if (tid == 0) {
        int s = 0;
        for (int i = 0; i < N_IMG; i++) { offsets[i] = s; s += counts[i]; }
    }
    __syncthreads();

    // Stable scatter: box order preserved within each bin.
    int base = offsets[wave];
    for (int i0 = 0; i0 < N_BOXES; i0 += 64) {
        int i = i0 + lane;
        bool p = (i < N_BOXES) && (box_idx[i] == wave);
        unsigned long long m = __ballot(p);
        unsigned long long below = m & ((1ull << lane) - 1ull);
        if (p) order[base + __popcll(below)] = i;
        base += __popcll(m);
    }
}

// Kernel B: one block = 256 consecutive output elements of one box;
// blocks walk boxes in n-grouped order so each 41 MB image slice stays
// hot in L2/LLC while all its boxes consume it.
__global__ __launch_bounds__(256) void crop_resize_kernel(
    const float* __restrict__ image,   // (8,256,200,200)
    const float* __restrict__ boxes,   // (1000,4)
    const int*   __restrict__ box_idx, // (1000,)
    const int*   __restrict__ order,   // (1000,) n-grouped box ids
    float*       __restrict__ out)     // (1000,256,14,14)
{
    int pos    = blockIdx.x / BLOCKS_PER_BOX;
    int within = blockIdx.x % BLOCKS_PER_BOX;
    int b      = order[pos];                   // uniform per block
    int elem   = within * 256 + threadIdx.x;   // [0, 50176)

    int x = elem % CROP_W;
    int t = elem / CROP_W;
    int y = t % CROP_H;
    int c = t / CROP_H;

    float y1 = boxes[b * 4 + 0];
    float x1 = boxes[b * 4 + 1];
    float y2 = boxes[b * 4 + 2];
    float x2 = boxes[b * 4 + 3];

    // Match reference arithmetic order exactly (IEEE divide, no fast-math).
    float h_scale = (y2 - y1) * (float)(IMG_H - 1) / (float)(CROP_H - 1);
    float w_scale = (x2 - x1) * (float)(IMG_W - 1) / (float)(CROP_W - 1);

    float in_y = y1 * (float)(IMG_H - 1) + (float)y * h_scale;
    float in_x = x1 * (float)(IMG_W - 1) + (float)x * w_scale;

    size_t oidx = ((size_t)b * IMG_C + c) * (CROP_H * CROP_W) + y * CROP_W + x;

    bool bad = (in_y > (float)(IMG_H - 1)) || (in_y < 0.0f) ||
               (in_x > (float)(IMG_W - 1)) || (in_x < 0.0f);
    if (bad) { out[oidx] = 0.0f; return; }

    int ty = (int)floorf(in_y);
    int by = (int)ceilf(in_y);
    int lx = (int)floorf(in_x);
    int rx = (int)ceilf(in_x);
    float yl = in_y - (float)ty;
    float xl = in_x - (float)lx;

    int n = box_idx[b];
    const float* __restrict__ plane =
        image + ((size_t)n * IMG_C + c) * (size_t)(IMG_H * IMG_W);

    float tl = plane[ty * IMG_W + lx];
    float tr = plane[ty * IMG_W + rx];
    float bl = plane[by * IMG_W + lx];
    float br = plane[by * IMG_W + rx];

    float top = tl + xl * (tr - tl);
    float bot = bl + xl * (br - bl);
    out[oidx] = top + yl * (bot - top);
}

extern "C" void kernel_launch(void* const* d_in, const int* in_sizes, int n_in,
                              void* d_out, int out_size, void* d_ws, size_t ws_size,
                              hipStream_t stream) {
    const float* image   = (const float*)d_in[0];
    const float* boxes   = (const float*)d_in[1];
    const int*   box_idx = (const int*)d_in[2];
    float* out  = (float*)d_out;
    int* order  = (int*)d_ws;   // 1000 ints, rewritten every call

    bin_boxes_kernel<<<1, 512, 0, stream>>>(box_idx, order);

    int grid = N_BOXES * BLOCKS_PER_BOX;  // 196,000
    crop_resize_kernel<<<grid, 256, 0, stream>>>(image, boxes, box_idx, order, out);
}